// Round 9
// baseline (121.776 us; speedup 1.0000x reference)
//
#include <hip/hip_runtime.h>
#include <math.h>

#define NN 50000
#define NE 800000
#define FIN 128
#define NC 10
#define NEG 0.2f

#define NB 196        // coarse buckets = ceil(NN/256), bucket = dst>>8
#define CHUNK 4096    // edges per pass1 block
#define P1B ((NE + CHUNK - 1) / CHUNK)   // 196 (last block: 1280 edges)
#define CAP 5120      // LDS capacity for one bucket in pass2 (max ~4400)
#define G1T ((NN + 127) / 128)           // 391 gemm1 tiles
#define LBW 200       // lbmat row stride (197 used, padded)
#define A1B 2048      // agg1 blocks (grid-stride, 8192 waves)

typedef unsigned int uint;
typedef unsigned char uchar;
typedef _Float16 h2 __attribute__((ext_vector_type(2)));
typedef __fp16 hb2 __attribute__((ext_vector_type(2)));
union U2H { uint u; h2 h; };

__device__ __forceinline__ uint pkrtz_u(float a, float b) {
    union { hb2 f; uint u; } r;
    r.f = __builtin_amdgcn_cvt_pkrtz(a, b);
    return r.u;
}

__device__ __forceinline__ float dot2f(h2 a, h2 b, float c) {
#if __has_builtin(__builtin_amdgcn_fdot2)
    return __builtin_amdgcn_fdot2(a, b, c, false);
#else
    return fmaf((float)a.x, (float)b.x, fmaf((float)a.y, (float)b.y, c));
#endif
}

__device__ __forceinline__ h2 lrelu2(h2 v) {
    return __builtin_elementwise_max(v, v * (_Float16)0.2f);
}

template<int CTRL>
__device__ __forceinline__ float dpp_add(float x) {
    int y = __builtin_amdgcn_update_dpp(0, __float_as_int(x), CTRL, 0xF, 0xF, true);
    return x + __int_as_float(y);
}
// sum over aligned 8-lane groups (= one head's 16 channels in half2 layout)
__device__ __forceinline__ float red8(float t) {
    t = dpp_add<0xB1>(t);
    t = dpp_add<0x4E>(t);
    t = dpp_add<0x141>(t);
    return t;
}

__device__ __forceinline__ int excl_scan256(int v, int* sc) {
    const int t = threadIdx.x;
    sc[t] = v;
    __syncthreads();
    for (int o = 1; o < 256; o <<= 1) {
        int u = (t >= o) ? sc[t - o] : 0;
        __syncthreads();
        sc[t] += u;
        __syncthreads();
    }
    return sc[t] - v;
}

// ---------------- fused kernel A: pass1 bucket-sort (deterministic) || gemm1(f16) ----------------

__device__ void pass1_body(const int* __restrict__ ei, uint* __restrict__ temp,
                           int* __restrict__ lbmat, char* smraw) {
    uint* pk = (uint*)smraw;                  // 16384 B [4096]
    int* h   = (int*)(smraw + 16384);         // 1024
    int* h2_ = (int*)(smraw + 17408);         // 1024
    int* sc  = (int*)(smraw + 18432);         // 1024
    const int t = threadIdx.x;
    const int B = blockIdx.x;
    const int e0 = B * CHUNK;
    const int cnt = min(CHUNK, NE - e0);

    h[t] = 0; h2_[t] = 0;
    __syncthreads();
    for (int i = t; i < cnt; i += 256) {
        int d = ei[NE + e0 + i];
        atomicAdd(&h[d >> 8], 1);
    }
    __syncthreads();
    const int hv = h[t];
    const int ex = excl_scan256(hv, sc);
    if (t < NB) lbmat[B * LBW + t] = ex;
    if (t == NB - 1) lbmat[B * LBW + NB] = ex + hv;   // = cnt
    h2_[t] = ex;   // reorder cursor starts at exclusive offset
    __syncthreads();
    for (int i = t; i < cnt; i += 256) {
        int s = ei[e0 + i];
        int d = ei[NE + e0 + i];
        int b = d >> 8;
        int pos = atomicAdd(&h2_[b], 1);
        pk[pos] = ((uint)s << 8) | ((uint)d & 255u);
    }
    __syncthreads();
    // fully coalesced contiguous dump
    for (int i = t; i < cnt; i += 256) temp[B * CHUNK + i] = pk[i];
}

// xl/xr stored as half2 pairs: oh2[n*32 + pair]
__device__ void gemm1_body(const float* __restrict__ x, const float* __restrict__ W,
                           uint* __restrict__ oh2, int n0, char* smraw) {
    uint (*Wsh)[64]  = (uint(*)[64])smraw;             // [64 kp][64 col] 16KB
    uint (*xTh)[128] = (uint(*)[128])(smraw + 16384);  // [16 kp][128 node] 8KB
    const int t = threadIdx.x;

    for (int i = t; i < 4096; i += 256) {   // stage W as k-paired half2
        int kp = i >> 6, col = i & 63;
        Wsh[kp][col] = pkrtz_u(W[(2 * kp) * 64 + col], W[(2 * kp + 1) * 64 + col]);
    }

    const int tn = t >> 4;          // node group: nodes tn*8..+7
    const int tc = t & 15;          // col group : cols tc*4..+3
    float acc[8][4] = {};
    const int sn = t >> 1;          // staging node 0..127
    const int kp0 = (t & 1) * 8;    // staging k-pair offset within chunk

    for (int kc = 0; kc < FIN; kc += 32) {
        __syncthreads();
        {
            int gn = n0 + sn;
            float4 v0, v1, v2, v3;
            if (gn < NN) {
                const float4* xr_ = (const float4*)(x + (size_t)gn * FIN + kc + kp0 * 2);
                v0 = xr_[0]; v1 = xr_[1]; v2 = xr_[2]; v3 = xr_[3];
            } else {
                v0 = v1 = v2 = v3 = make_float4(0.f, 0.f, 0.f, 0.f);
            }
            xTh[kp0 + 0][sn] = pkrtz_u(v0.x, v0.y);
            xTh[kp0 + 1][sn] = pkrtz_u(v0.z, v0.w);
            xTh[kp0 + 2][sn] = pkrtz_u(v1.x, v1.y);
            xTh[kp0 + 3][sn] = pkrtz_u(v1.z, v1.w);
            xTh[kp0 + 4][sn] = pkrtz_u(v2.x, v2.y);
            xTh[kp0 + 5][sn] = pkrtz_u(v2.z, v2.w);
            xTh[kp0 + 6][sn] = pkrtz_u(v3.x, v3.y);
            xTh[kp0 + 7][sn] = pkrtz_u(v3.z, v3.w);
        }
        __syncthreads();
        const int kpc = kc >> 1;
#pragma unroll
        for (int kp = 0; kp < 16; ++kp) {
            uint4 wv = *(const uint4*)&Wsh[kpc + kp][tc * 4];
            uint4 xa = *(const uint4*)&xTh[kp][tn * 8];
            uint4 xb = *(const uint4*)&xTh[kp][tn * 8 + 4];
            U2H w0, w1, w2, w3, x0, x1, x2, x3, x4, x5, x6, x7;
            w0.u = wv.x; w1.u = wv.y; w2.u = wv.z; w3.u = wv.w;
            x0.u = xa.x; x1.u = xa.y; x2.u = xa.z; x3.u = xa.w;
            x4.u = xb.x; x5.u = xb.y; x6.u = xb.z; x7.u = xb.w;
            h2 xs[8] = {x0.h, x1.h, x2.h, x3.h, x4.h, x5.h, x6.h, x7.h};
#pragma unroll
            for (int i = 0; i < 8; ++i) {
                acc[i][0] = dot2f(xs[i], w0.h, acc[i][0]);
                acc[i][1] = dot2f(xs[i], w1.h, acc[i][1]);
                acc[i][2] = dot2f(xs[i], w2.h, acc[i][2]);
                acc[i][3] = dot2f(xs[i], w3.h, acc[i][3]);
            }
        }
    }
#pragma unroll
    for (int i = 0; i < 8; ++i) {
        int n = n0 + tn * 8 + i;
        if (n < NN) {
            uint p0 = pkrtz_u(acc[i][0], acc[i][1]);
            uint p1 = pkrtz_u(acc[i][2], acc[i][3]);
            *(uint2*)&oh2[(size_t)n * 32 + tc * 2] = make_uint2(p0, p1);
        }
    }
}

__global__ __launch_bounds__(256) void k_fusedA(const float* __restrict__ x,
                                                const int* __restrict__ ei,
                                                const float* __restrict__ W1l,
                                                const float* __restrict__ W1r,
                                                uint* __restrict__ xlh2,
                                                uint* __restrict__ xrh2,
                                                uint* __restrict__ temp,
                                                int* __restrict__ lbmat) {
    __shared__ __align__(16) char smraw[25600];
    if (blockIdx.x < P1B) {
        pass1_body(ei, temp, lbmat, smraw);
    } else {
        int g = blockIdx.x - P1B;
        bool left = g < G1T;
        int n0 = (left ? g : g - G1T) * 128;
        gemm1_body(x, left ? W1l : W1r, left ? xlh2 : xrh2, n0, smraw);
    }
}

// ---------------- pass2: pull-based per-bucket CSR (no global atomics) ----------------

__global__ __launch_bounds__(256) void k_pass2(const uint* __restrict__ temp,
                                               const int* __restrict__ lbmat,
                                               int* __restrict__ rowptr,
                                               int* __restrict__ deg,
                                               int* __restrict__ csr_src) {
    __shared__ uint P[CAP];
    __shared__ int nh[256], nbx[256], ncur[256], sc[256];
    const int t = threadIdx.x;
    const int b = blockIdx.x;

    // run info for this bucket from every pass1 block
    int lbv = 0, len = 0;
    if (t < P1B) {
        lbv = lbmat[t * LBW + b];
        len = lbmat[t * LBW + b + 1] - lbv;
    }
    const int colstart = excl_scan256(len, sc);
    __syncthreads();
    const int cnt = sc[255];                 // total edges in this bucket
    __syncthreads();
    (void)excl_scan256(lbv, sc);
    __syncthreads();
    const int csrbase = sc[255];             // = sum_B lbmat[B][b] (telescoping prefix)
    __syncthreads();
    nh[t] = 0; ncur[t] = 0;
    __syncthreads();
    // gather this bucket's runs into LDS
    if (t < P1B) {
        const uint* src = temp + t * CHUNK + lbv;
        for (int i = 0; i < len; ++i) P[colstart + i] = src[i];
    }
    __syncthreads();
    for (int i = t; i < cnt; i += 256) atomicAdd(&nh[P[i] & 255u], 1);
    __syncthreads();
    const int c = nh[t];
    const int nb_ex = excl_scan256(c, sc);
    nbx[t] = nb_ex;
    const int gnode = b * 256 + t;
    if (gnode < NN) { rowptr[gnode] = csrbase + nb_ex; deg[gnode] = c; }
    __syncthreads();
    for (int i = t; i < cnt; i += 256) {
        uint v = P[i];
        int l = (int)(v & 255u);
        int r = atomicAdd(&ncur[l], 1);
        csr_src[csrbase + nbx[l] + r] = (int)(v >> 8);
    }
    // zero the slack so agg batches can safely over-read
    if (b == 0 && t < 64) csr_src[NE + t] = 0;
}

// ---------------- layer 1 aggregate: scalar src-idx loads, 8 edges in flight ----------------

__global__ __launch_bounds__(256) void k_agg1(const uint* __restrict__ xlh2,
                                              const uint* __restrict__ xrh2,
                                              const int* __restrict__ rowptr,
                                              const int* __restrict__ deg,
                                              const int* __restrict__ csr_src,
                                              const float* __restrict__ att1,
                                              const float* __restrict__ b1,
                                              uint* __restrict__ hbh2) {
    const int lane = threadIdx.x & 63;
    const int fl = lane & 31;        // feature-pair
    const int hid = lane >> 5;       // edge-half id
    float2 av = *(const float2*)&att1[2 * fl];
    U2H att; att.u = pkrtz_u(av.x, av.y);
    float2 bv = *(const float2*)&b1[2 * fl];
    const int wave0 = __builtin_amdgcn_readfirstlane(blockIdx.x * 4 + (threadIdx.x >> 6));

    for (int node = wave0; node < NN; node += A1B * 4) {
        U2H xrf; xrf.u = xrh2[(size_t)node * 32 + fl];
        const int start = rowptr[node];          // scalar (node uniform)
        const int dg = deg[node];                // scalar
        const int* sp = csr_src + start;

        float denom = 0.f, acc0 = 0.f, acc1 = 0.f;
        const int niter = (dg + 1) >> 1;         // 2 edges per iter (hid split)
        for (int jj = 0; jj < niter; jj += 4) {
            int e8[8];
#pragma unroll
            for (int k = 0; k < 8; ++k) e8[k] = sp[2 * jj + k];   // s_loads
            U2H v[4];
#pragma unroll
            for (int k = 0; k < 4; ++k) {
                int src = hid ? e8[2 * k + 1] : e8[2 * k];
                v[k].u = xlh2[(size_t)src * 32 + fl];
            }
#pragma unroll
            for (int k = 0; k < 4; ++k) {
                float tl = red8(dot2f(lrelu2(v[k].h + xrf.h), att.h, 0.f));
                float e = (2 * (jj + k) + hid < dg) ? __expf(tl) : 0.f;
                denom += e;
                acc0 = fmaf(e, (float)v[k].h.x, acc0);
                acc1 = fmaf(e, (float)v[k].h.y, acc1);
            }
        }
        denom += __shfl_xor(denom, 32);
        acc0  += __shfl_xor(acc0, 32);
        acc1  += __shfl_xor(acc1, 32);
        if (lane < 32) {
            float r = (dg > 0) ? (1.0f / denom) : 0.f;
            float o0 = fmaf(acc0, r, bv.x);
            float o1 = fmaf(acc1, r, bv.y);
            o0 = o0 > 0.f ? o0 : expm1f(o0);
            o1 = o1 > 0.f ? o1 : expm1f(o1);
            hbh2[(size_t)node * 32 + fl] = pkrtz_u(o0, o1);
        }
    }
}

// ---------------- layer 2 GEMM: node per thread, packed half2 outputs ----------------

__global__ __launch_bounds__(256) void k_gemm2(const uint* __restrict__ hbh2,
                                               const float* __restrict__ W2l,
                                               const float* __restrict__ W2r,
                                               uint* __restrict__ xl2h,
                                               uint* __restrict__ xr2h) {
    int n = blockIdx.x * 256 + threadIdx.x;
    if (n >= NN) return;
    float al[NC] = {}, ar[NC] = {};
    const uint4* hr4 = (const uint4*)(hbh2 + (size_t)n * 32);
#pragma unroll
    for (int q = 0; q < 8; ++q) {
        uint4 qq = hr4[q];
        uint uu[4] = {qq.x, qq.y, qq.z, qq.w};
#pragma unroll
        for (int j = 0; j < 4; ++j) {
            U2H hh; hh.u = uu[j];
            float f0 = (float)hh.h.x, f1 = (float)hh.h.y;
            int k = q * 8 + j * 2;
            const float* wl0 = W2l + k * NC;
            const float* wr0 = W2r + k * NC;
#pragma unroll
            for (int c = 0; c < NC; ++c) {
                al[c] = fmaf(f0, wl0[c], fmaf(f1, wl0[NC + c], al[c]));
                ar[c] = fmaf(f0, wr0[c], fmaf(f1, wr0[NC + c], ar[c]));
            }
        }
    }
    uint p0 = pkrtz_u(al[0], al[1]);
    uint p1 = pkrtz_u(al[2], al[3]);
    uint p2 = pkrtz_u(al[4], al[5]);
    uint p3 = pkrtz_u(al[6], al[7]);
    uint p4 = pkrtz_u(al[8], al[9]);
    *(uint4*)&xl2h[(size_t)n * 8]     = make_uint4(p0, p1, p2, p3);
    *(uint4*)&xl2h[(size_t)n * 8 + 4] = make_uint4(p4, 0u, 0u, 0u);
    p0 = pkrtz_u(ar[0], ar[1]);
    p1 = pkrtz_u(ar[2], ar[3]);
    p2 = pkrtz_u(ar[4], ar[5]);
    p3 = pkrtz_u(ar[6], ar[7]);
    p4 = pkrtz_u(ar[8], ar[9]);
    *(uint4*)&xr2h[(size_t)n * 8]     = make_uint4(p0, p1, p2, p3);
    *(uint4*)&xr2h[(size_t)n * 8 + 4] = make_uint4(p4, 0u, 0u, 0u);
}

// ---------------- layer 2 aggregate: masked batch of 4 (32 edges/wave in flight) ----------------

__global__ __launch_bounds__(256) void k_agg2(const uint* __restrict__ xl2h,
                                              const uint* __restrict__ xr2h,
                                              const int* __restrict__ rowptr,
                                              const int* __restrict__ deg,
                                              const int* __restrict__ csr_src,
                                              const float* __restrict__ att2,
                                              const float* __restrict__ b2,
                                              float* __restrict__ out) {
    const int node = blockIdx.x * 4 + (threadIdx.x >> 6);
    if (node >= NN) return;
    const int lane = threadIdx.x & 63;
    const int fp = lane & 7;         // feature-pair (0..4 real, 5..7 pad)
    const int eg = lane >> 3;        // edge group 0..7
    U2H att;
    if (fp < 5) {
        float2 av = *(const float2*)&att2[2 * fp];
        att.u = pkrtz_u(av.x, av.y);
    } else {
        att.u = 0;
    }
    U2H xrf; xrf.u = xr2h[(size_t)node * 8 + fp];
    const int start = rowptr[node];
    const int dg = deg[node];
    const int permbase = eg * 4;

    float denom = 0.f, acc0 = 0.f, acc1 = 0.f;
    for (int base = 0; base < dg; base += 64) {
        int idx = base + lane;
        int srcs = (idx < dg) ? csr_src[start + idx] : 0;
        int rem = dg - base; if (rem > 64) rem = 64;
        int iters = (rem + 7) >> 3;
        int thr = (rem - eg + 7) >> 3;       // edge (8j+eg) valid iff j < thr
        for (int jj = 0; jj < iters; jj += 4) {
            int s[4]; U2H v[4];
#pragma unroll
            for (int k = 0; k < 4; ++k)
                s[k] = __builtin_amdgcn_ds_bpermute((jj + k) * 32 + permbase, srcs);
#pragma unroll
            for (int k = 0; k < 4; ++k)
                v[k].u = xl2h[(size_t)s[k] * 8 + fp];
#pragma unroll
            for (int k = 0; k < 4; ++k) {
                float tl = red8(dot2f(lrelu2(v[k].h + xrf.h), att.h, 0.f));
                float e = (jj + k < thr) ? __expf(tl) : 0.f;
                denom += e;
                acc0 = fmaf(e, (float)v[k].h.x, acc0);
                acc1 = fmaf(e, (float)v[k].h.y, acc1);
            }
        }
    }
#pragma unroll
    for (int m = 8; m <= 32; m <<= 1) {
        denom += __shfl_xor(denom, m);
        acc0  += __shfl_xor(acc0, m);
        acc1  += __shfl_xor(acc1, m);
    }
    if (lane < 5) {   // eg==0, fp<5
        float r = (dg > 0) ? (1.0f / denom) : 0.f;
        float2 o;
        o.x = fmaf(acc0, r, b2[2 * fp]);
        o.y = fmaf(acc1, r, b2[2 * fp + 1]);
        *(float2*)&out[(size_t)node * NC + 2 * fp] = o;
    }
}

// ---------------- launch ----------------

extern "C" void kernel_launch(void* const* d_in, const int* in_sizes, int n_in,
                              void* d_out, int out_size, void* d_ws, size_t ws_size,
                              hipStream_t stream) {
    const float* x    = (const float*)d_in[0];
    const int*   ei   = (const int*)d_in[1];
    const float* W1l  = (const float*)d_in[2];
    const float* W1r  = (const float*)d_in[3];
    const float* att1 = (const float*)d_in[4];
    const float* b1   = (const float*)d_in[5];
    const float* W2l  = (const float*)d_in[6];
    const float* W2r  = (const float*)d_in[7];
    const float* att2 = (const float*)d_in[8];
    const float* b2   = (const float*)d_in[9];
    float* out = (float*)d_out;

    char* w = (char*)d_ws;
    size_t off = 0;
    auto alloc = [&](size_t bytes) -> void* {
        void* p = w + off;
        off = (off + bytes + 255) & ~(size_t)255;
        return p;
    };
    uint* xlh2   = (uint*)alloc((size_t)NN * 32 * 4);
    uint* xrh2   = (uint*)alloc((size_t)NN * 32 * 4);
    uint* hbh2   = (uint*)alloc((size_t)NN * 32 * 4);
    uint* xl2h   = (uint*)alloc((size_t)NN * 8 * 4);
    uint* xr2h   = (uint*)alloc((size_t)NN * 8 * 4);
    uint* temp   = (uint*)alloc((size_t)P1B * CHUNK * 4);
    int*  lbmat  = (int*)alloc((size_t)P1B * LBW * 4);
    int*  rowptr = (int*)alloc((size_t)NN * 4);
    int*  deg    = (int*)alloc((size_t)NN * 4);
    int*  csr_src = (int*)alloc((size_t)(NE + 64) * 4);

    k_fusedA<<<P1B + 2 * G1T, 256, 0, stream>>>(x, ei, W1l, W1r, xlh2, xrh2, temp, lbmat);
    k_pass2<<<NB, 256, 0, stream>>>(temp, lbmat, rowptr, deg, csr_src);
    k_agg1<<<A1B, 256, 0, stream>>>(xlh2, xrh2, rowptr, deg, csr_src, att1, b1, hbh2);
    k_gemm2<<<(NN + 255) / 256, 256, 0, stream>>>(hbh2, W2l, W2r, xl2h, xr2h);
    k_agg2<<<(NN + 3) / 4, 256, 0, stream>>>(xl2h, xr2h, rowptr, deg, csr_src, att2, b2, out);
}

// Round 10
// 110.841 us; speedup vs baseline: 1.0987x; 1.0987x over previous
//
#include <hip/hip_runtime.h>
#include <math.h>

#define NN 50000
#define NE 800000
#define FIN 128
#define NC 10
#define NEG 0.2f

#define NB 196        // coarse buckets = ceil(NN/256), bucket = dst>>8
#define CHUNK 4096    // edges per pass1 block
#define P1B ((NE + CHUNK - 1) / CHUNK)   // 196 (last block: 1280 edges)
#define CAP 5120      // LDS capacity for one bucket in pass2
#define G1T ((NN + 255) / 256)           // 196 gemm1 tiles (256 nodes each)
#define LBW 200       // lbmat row stride

typedef unsigned int uint;
typedef unsigned char uchar;
typedef _Float16 h2 __attribute__((ext_vector_type(2)));
typedef __fp16 hb2 __attribute__((ext_vector_type(2)));
union U2H { uint u; h2 h; };

__device__ __forceinline__ uint pkrtz_u(float a, float b) {
    union { hb2 f; uint u; } r;
    r.f = __builtin_amdgcn_cvt_pkrtz(a, b);
    return r.u;
}

__device__ __forceinline__ float dot2f(h2 a, h2 b, float c) {
#if __has_builtin(__builtin_amdgcn_fdot2)
    return __builtin_amdgcn_fdot2(a, b, c, false);
#else
    return fmaf((float)a.x, (float)b.x, fmaf((float)a.y, (float)b.y, c));
#endif
}

__device__ __forceinline__ h2 lrelu2(h2 v) {
    return __builtin_elementwise_max(v, v * (_Float16)0.2f);
}

template<int CTRL>
__device__ __forceinline__ float dpp_add(float x) {
    int y = __builtin_amdgcn_update_dpp(0, __float_as_int(x), CTRL, 0xF, 0xF, true);
    return x + __int_as_float(y);
}
// sum over aligned 8-lane groups (= one head's 16 channels in half2 layout)
__device__ __forceinline__ float red8(float t) {
    t = dpp_add<0xB1>(t);
    t = dpp_add<0x4E>(t);
    t = dpp_add<0x141>(t);
    return t;
}

__device__ __forceinline__ int excl_scan256(int v, int* sc) {
    const int t = threadIdx.x;
    sc[t] = v;
    __syncthreads();
    for (int o = 1; o < 256; o <<= 1) {
        int u = (t >= o) ? sc[t - o] : 0;
        __syncthreads();
        sc[t] += u;
        __syncthreads();
    }
    return sc[t] - v;
}

// ---------------- fused kernel A: pass1 bucket-sort (deterministic) || gemm1(f16) ----------------

__device__ void pass1_body(const int* __restrict__ ei, uint* __restrict__ temp,
                           int* __restrict__ lbmat, char* smraw) {
    uint* pk = (uint*)smraw;                  // 16384 B [4096]
    int* h   = (int*)(smraw + 16384);         // 1024
    int* h2_ = (int*)(smraw + 17408);         // 1024
    int* sc  = (int*)(smraw + 18432);         // 1024
    const int t = threadIdx.x;
    const int B = blockIdx.x;
    const int e0 = B * CHUNK;
    const int cnt = min(CHUNK, NE - e0);

    h[t] = 0; h2_[t] = 0;
    __syncthreads();
    for (int i = t; i < cnt; i += 256) {
        int d = ei[NE + e0 + i];
        atomicAdd(&h[d >> 8], 1);
    }
    __syncthreads();
    const int hv = h[t];
    const int ex = excl_scan256(hv, sc);
    if (t < NB) lbmat[B * LBW + t] = ex;
    if (t == NB - 1) lbmat[B * LBW + NB] = ex + hv;   // = cnt
    h2_[t] = ex;
    __syncthreads();
    for (int i = t; i < cnt; i += 256) {
        int s = ei[e0 + i];
        int d = ei[NE + e0 + i];
        int b = d >> 8;
        int pos = atomicAdd(&h2_[b], 1);
        pk[pos] = ((uint)s << 8) | ((uint)d & 255u);
    }
    __syncthreads();
    for (int i = t; i < cnt; i += 256) temp[B * CHUNK + i] = pk[i];
}

// gemm1: tile 256 nodes x 64 cols, thread = 8 nodes x 8 cols (f16 dot2)
__device__ void gemm1_body(const float* __restrict__ x, const float* __restrict__ W,
                           uint* __restrict__ oh2, int n0, char* smraw) {
    uint (*Wsh)[64]  = (uint(*)[64])smraw;             // [64 kp][64 col] 16KB
    uint (*xTh)[256] = (uint(*)[256])(smraw + 16384);  // [16 kp][256 node] 16KB
    const int t = threadIdx.x;

    for (int i = t; i < 4096; i += 256) {   // stage W as k-paired half2
        int kp = i >> 6, col = i & 63;
        Wsh[kp][col] = pkrtz_u(W[(2 * kp) * 64 + col], W[(2 * kp + 1) * 64 + col]);
    }

    const int tn = t >> 3;          // node group: nodes tn*8..+7  (0..31)
    const int tc = t & 7;           // col group : cols tc*8..+7   (0..7)
    float acc[8][8] = {};

    for (int kc = 0; kc < FIN; kc += 32) {
        __syncthreads();
        {   // stage x: thread t loads node n0+t's 32 k-values of this chunk
            int gn = n0 + t;
            float4 v[8];
            if (gn < NN) {
                const float4* xr_ = (const float4*)(x + (size_t)gn * FIN + kc);
#pragma unroll
                for (int q = 0; q < 8; ++q) v[q] = xr_[q];
            } else {
#pragma unroll
                for (int q = 0; q < 8; ++q) v[q] = make_float4(0.f, 0.f, 0.f, 0.f);
            }
#pragma unroll
            for (int q = 0; q < 8; ++q) {
                xTh[2 * q + 0][t] = pkrtz_u(v[q].x, v[q].y);
                xTh[2 * q + 1][t] = pkrtz_u(v[q].z, v[q].w);
            }
        }
        __syncthreads();
        const int kpc = kc >> 1;
#pragma unroll
        for (int kp = 0; kp < 16; ++kp) {
            uint4 wa = *(const uint4*)&Wsh[kpc + kp][tc * 8];
            uint4 wb = *(const uint4*)&Wsh[kpc + kp][tc * 8 + 4];
            uint4 xa = *(const uint4*)&xTh[kp][tn * 8];
            uint4 xb = *(const uint4*)&xTh[kp][tn * 8 + 4];
            uint wu[8] = {wa.x, wa.y, wa.z, wa.w, wb.x, wb.y, wb.z, wb.w};
            uint xu[8] = {xa.x, xa.y, xa.z, xa.w, xb.x, xb.y, xb.z, xb.w};
#pragma unroll
            for (int i = 0; i < 8; ++i) {
                U2H xi; xi.u = xu[i];
#pragma unroll
                for (int j = 0; j < 8; ++j) {
                    U2H wj; wj.u = wu[j];
                    acc[i][j] = dot2f(xi.h, wj.h, acc[i][j]);
                }
            }
        }
    }
#pragma unroll
    for (int i = 0; i < 8; ++i) {
        int n = n0 + tn * 8 + i;
        if (n < NN) {
            uint4 o;
            o.x = pkrtz_u(acc[i][0], acc[i][1]);
            o.y = pkrtz_u(acc[i][2], acc[i][3]);
            o.z = pkrtz_u(acc[i][4], acc[i][5]);
            o.w = pkrtz_u(acc[i][6], acc[i][7]);
            *(uint4*)&oh2[(size_t)n * 32 + tc * 4] = o;
        }
    }
}

__global__ __launch_bounds__(256) void k_fusedA(const float* __restrict__ x,
                                                const int* __restrict__ ei,
                                                const float* __restrict__ W1l,
                                                const float* __restrict__ W1r,
                                                uint* __restrict__ xlh2,
                                                uint* __restrict__ xrh2,
                                                uint* __restrict__ temp,
                                                int* __restrict__ lbmat) {
    __shared__ __align__(16) char smraw[32768];
    if (blockIdx.x < P1B) {
        pass1_body(ei, temp, lbmat, smraw);
    } else {
        int g = blockIdx.x - P1B;
        bool left = g < G1T;
        int n0 = (left ? g : g - G1T) * 256;
        gemm1_body(x, left ? W1l : W1r, left ? xlh2 : xrh2, n0, smraw);
    }
}

// ---------------- pass2: pull-based per-bucket CSR (no global atomics) ----------------

__global__ __launch_bounds__(256) void k_pass2(const uint* __restrict__ temp,
                                               const int* __restrict__ lbmat,
                                               int* __restrict__ rowptr,
                                               int* __restrict__ deg,
                                               int* __restrict__ csr_src) {
    __shared__ uint P[CAP];
    __shared__ int nh[256], nbx[256], ncur[256], sc[256];
    const int t = threadIdx.x;
    const int b = blockIdx.x;

    int lbv = 0, len = 0;
    if (t < P1B) {
        lbv = lbmat[t * LBW + b];
        len = lbmat[t * LBW + b + 1] - lbv;
    }
    const int colstart = excl_scan256(len, sc);
    __syncthreads();
    const int cnt = sc[255];
    __syncthreads();
    (void)excl_scan256(lbv, sc);
    __syncthreads();
    const int csrbase = sc[255];
    __syncthreads();
    nh[t] = 0; ncur[t] = 0;
    __syncthreads();
    if (t < P1B) {
        const uint* src = temp + t * CHUNK + lbv;
        for (int i = 0; i < len; ++i) P[colstart + i] = src[i];
    }
    __syncthreads();
    for (int i = t; i < cnt; i += 256) atomicAdd(&nh[P[i] & 255u], 1);
    __syncthreads();
    const int c = nh[t];
    const int nb_ex = excl_scan256(c, sc);
    nbx[t] = nb_ex;
    const int gnode = b * 256 + t;
    if (gnode < NN) { rowptr[gnode] = csrbase + nb_ex; deg[gnode] = c; }
    __syncthreads();
    for (int i = t; i < cnt; i += 256) {
        uint v = P[i];
        int l = (int)(v & 255u);
        int r = atomicAdd(&ncur[l], 1);
        csr_src[csrbase + nbx[l] + r] = (int)(v >> 8);
    }
}

// ---------------- layer 1 aggregate: bpermute, 4-edge-pair pipelined (R7 form) ----------------

__global__ __launch_bounds__(256) void k_agg1(const uint* __restrict__ xlh2,
                                              const uint* __restrict__ xrh2,
                                              const int* __restrict__ rowptr,
                                              const int* __restrict__ deg,
                                              const int* __restrict__ csr_src,
                                              const float* __restrict__ att1,
                                              const float* __restrict__ b1,
                                              uint* __restrict__ hbh2) {
    const int node = blockIdx.x * 4 + (threadIdx.x >> 6);
    if (node >= NN) return;
    const int lane = threadIdx.x & 63;
    const int fl = lane & 31;        // feature-pair
    const int hid = lane >> 5;       // edge-half id
    float2 av = *(const float2*)&att1[2 * fl];
    U2H att; att.u = pkrtz_u(av.x, av.y);
    U2H xrf; xrf.u = xrh2[(size_t)node * 32 + fl];
    const int start = rowptr[node];
    const int dg = deg[node];
    const int permbase = (lane & 32) >> 3;   // 0 or 4

    float denom = 0.f, acc0 = 0.f, acc1 = 0.f;
    for (int base = 0; base < dg; base += 64) {
        int idx = base + lane;
        int srcs = (idx < dg) ? csr_src[start + idx] : 0;
        int rem = dg - base; if (rem > 64) rem = 64;
        int iters = (rem + 1) >> 1;
        int thr = (rem - hid + 1) >> 1;      // edge (2j+hid) valid iff j < thr
        int jj = 0;
        for (; jj + 4 <= iters; jj += 4) {
            int s0 = __builtin_amdgcn_ds_bpermute(jj * 8 +  0 + permbase, srcs);
            int s1 = __builtin_amdgcn_ds_bpermute(jj * 8 +  8 + permbase, srcs);
            int s2 = __builtin_amdgcn_ds_bpermute(jj * 8 + 16 + permbase, srcs);
            int s3 = __builtin_amdgcn_ds_bpermute(jj * 8 + 24 + permbase, srcs);
            U2H v0; v0.u = xlh2[(size_t)s0 * 32 + fl];
            U2H v1; v1.u = xlh2[(size_t)s1 * 32 + fl];
            U2H v2; v2.u = xlh2[(size_t)s2 * 32 + fl];
            U2H v3; v3.u = xlh2[(size_t)s3 * 32 + fl];
            float t0 = red8(dot2f(lrelu2(v0.h + xrf.h), att.h, 0.f));
            float t1 = red8(dot2f(lrelu2(v1.h + xrf.h), att.h, 0.f));
            float t2 = red8(dot2f(lrelu2(v2.h + xrf.h), att.h, 0.f));
            float t3 = red8(dot2f(lrelu2(v3.h + xrf.h), att.h, 0.f));
            float e0 = (jj + 0 < thr) ? __expf(t0) : 0.f;
            float e1 = (jj + 1 < thr) ? __expf(t1) : 0.f;
            float e2 = (jj + 2 < thr) ? __expf(t2) : 0.f;
            float e3 = (jj + 3 < thr) ? __expf(t3) : 0.f;
            denom += (e0 + e1) + (e2 + e3);
            acc0 = fmaf(e0, (float)v0.h.x, acc0);
            acc0 = fmaf(e1, (float)v1.h.x, acc0);
            acc0 = fmaf(e2, (float)v2.h.x, acc0);
            acc0 = fmaf(e3, (float)v3.h.x, acc0);
            acc1 = fmaf(e0, (float)v0.h.y, acc1);
            acc1 = fmaf(e1, (float)v1.h.y, acc1);
            acc1 = fmaf(e2, (float)v2.h.y, acc1);
            acc1 = fmaf(e3, (float)v3.h.y, acc1);
        }
        for (; jj < iters; ++jj) {
            int s0 = __builtin_amdgcn_ds_bpermute(jj * 8 + permbase, srcs);
            U2H v0; v0.u = xlh2[(size_t)s0 * 32 + fl];
            float t0 = red8(dot2f(lrelu2(v0.h + xrf.h), att.h, 0.f));
            float e0 = (jj < thr) ? __expf(t0) : 0.f;
            denom += e0;
            acc0 = fmaf(e0, (float)v0.h.x, acc0);
            acc1 = fmaf(e0, (float)v0.h.y, acc1);
        }
    }
    denom += __shfl_xor(denom, 32);
    acc0  += __shfl_xor(acc0, 32);
    acc1  += __shfl_xor(acc1, 32);
    if (lane < 32) {
        float r = (dg > 0) ? (1.0f / denom) : 0.f;
        float2 bv = *(const float2*)&b1[2 * fl];
        float o0 = fmaf(acc0, r, bv.x);
        float o1 = fmaf(acc1, r, bv.y);
        o0 = o0 > 0.f ? o0 : expm1f(o0);
        o1 = o1 > 0.f ? o1 : expm1f(o1);
        hbh2[(size_t)node * 32 + fl] = pkrtz_u(o0, o1);
    }
}

// ---------------- layer 2 GEMM: node per thread, packed half2 outputs ----------------

__global__ __launch_bounds__(256) void k_gemm2(const uint* __restrict__ hbh2,
                                               const float* __restrict__ W2l,
                                               const float* __restrict__ W2r,
                                               uint* __restrict__ xl2h,
                                               uint* __restrict__ xr2h) {
    int n = blockIdx.x * 256 + threadIdx.x;
    if (n >= NN) return;
    float al[NC] = {}, ar[NC] = {};
    const uint4* hr4 = (const uint4*)(hbh2 + (size_t)n * 32);
#pragma unroll
    for (int q = 0; q < 8; ++q) {
        uint4 qq = hr4[q];
        uint uu[4] = {qq.x, qq.y, qq.z, qq.w};
#pragma unroll
        for (int j = 0; j < 4; ++j) {
            U2H hh; hh.u = uu[j];
            float f0 = (float)hh.h.x, f1 = (float)hh.h.y;
            int k = q * 8 + j * 2;
            const float* wl0 = W2l + k * NC;
            const float* wr0 = W2r + k * NC;
#pragma unroll
            for (int c = 0; c < NC; ++c) {
                al[c] = fmaf(f0, wl0[c], fmaf(f1, wl0[NC + c], al[c]));
                ar[c] = fmaf(f0, wr0[c], fmaf(f1, wr0[NC + c], ar[c]));
            }
        }
    }
    uint p0 = pkrtz_u(al[0], al[1]);
    uint p1 = pkrtz_u(al[2], al[3]);
    uint p2 = pkrtz_u(al[4], al[5]);
    uint p3 = pkrtz_u(al[6], al[7]);
    uint p4 = pkrtz_u(al[8], al[9]);
    *(uint4*)&xl2h[(size_t)n * 8]     = make_uint4(p0, p1, p2, p3);
    *(uint4*)&xl2h[(size_t)n * 8 + 4] = make_uint4(p4, 0u, 0u, 0u);
    p0 = pkrtz_u(ar[0], ar[1]);
    p1 = pkrtz_u(ar[2], ar[3]);
    p2 = pkrtz_u(ar[4], ar[5]);
    p3 = pkrtz_u(ar[6], ar[7]);
    p4 = pkrtz_u(ar[8], ar[9]);
    *(uint4*)&xr2h[(size_t)n * 8]     = make_uint4(p0, p1, p2, p3);
    *(uint4*)&xr2h[(size_t)n * 8 + 4] = make_uint4(p4, 0u, 0u, 0u);
}

// ---------------- layer 2 aggregate: masked batch of 4 (32 edges/wave in flight) ----------------

__global__ __launch_bounds__(256) void k_agg2(const uint* __restrict__ xl2h,
                                              const uint* __restrict__ xr2h,
                                              const int* __restrict__ rowptr,
                                              const int* __restrict__ deg,
                                              const int* __restrict__ csr_src,
                                              const float* __restrict__ att2,
                                              const float* __restrict__ b2,
                                              float* __restrict__ out) {
    const int node = blockIdx.x * 4 + (threadIdx.x >> 6);
    if (node >= NN) return;
    const int lane = threadIdx.x & 63;
    const int fp = lane & 7;         // feature-pair (0..4 real, 5..7 pad)
    const int eg = lane >> 3;        // edge group 0..7
    U2H att;
    if (fp < 5) {
        float2 av = *(const float2*)&att2[2 * fp];
        att.u = pkrtz_u(av.x, av.y);
    } else {
        att.u = 0;
    }
    U2H xrf; xrf.u = xr2h[(size_t)node * 8 + fp];
    const int start = rowptr[node];
    const int dg = deg[node];
    const int permbase = eg * 4;

    float denom = 0.f, acc0 = 0.f, acc1 = 0.f;
    for (int base = 0; base < dg; base += 64) {
        int idx = base + lane;
        int srcs = (idx < dg) ? csr_src[start + idx] : 0;
        int rem = dg - base; if (rem > 64) rem = 64;
        int iters = (rem + 7) >> 3;
        int thr = (rem - eg + 7) >> 3;
        for (int jj = 0; jj < iters; jj += 4) {
            int s[4]; U2H v[4];
#pragma unroll
            for (int k = 0; k < 4; ++k)
                s[k] = __builtin_amdgcn_ds_bpermute((jj + k) * 32 + permbase, srcs);
#pragma unroll
            for (int k = 0; k < 4; ++k)
                v[k].u = xl2h[(size_t)s[k] * 8 + fp];
#pragma unroll
            for (int k = 0; k < 4; ++k) {
                float tl = red8(dot2f(lrelu2(v[k].h + xrf.h), att.h, 0.f));
                float e = (jj + k < thr) ? __expf(tl) : 0.f;
                denom += e;
                acc0 = fmaf(e, (float)v[k].h.x, acc0);
                acc1 = fmaf(e, (float)v[k].h.y, acc1);
            }
        }
    }
#pragma unroll
    for (int m = 8; m <= 32; m <<= 1) {
        denom += __shfl_xor(denom, m);
        acc0  += __shfl_xor(acc0, m);
        acc1  += __shfl_xor(acc1, m);
    }
    if (lane < 5) {
        float r = (dg > 0) ? (1.0f / denom) : 0.f;
        float2 o;
        o.x = fmaf(acc0, r, b2[2 * fp]);
        o.y = fmaf(acc1, r, b2[2 * fp + 1]);
        *(float2*)&out[(size_t)node * NC + 2 * fp] = o;
    }
}

// ---------------- launch ----------------

extern "C" void kernel_launch(void* const* d_in, const int* in_sizes, int n_in,
                              void* d_out, int out_size, void* d_ws, size_t ws_size,
                              hipStream_t stream) {
    const float* x    = (const float*)d_in[0];
    const int*   ei   = (const int*)d_in[1];
    const float* W1l  = (const float*)d_in[2];
    const float* W1r  = (const float*)d_in[3];
    const float* att1 = (const float*)d_in[4];
    const float* b1   = (const float*)d_in[5];
    const float* W2l  = (const float*)d_in[6];
    const float* W2r  = (const float*)d_in[7];
    const float* att2 = (const float*)d_in[8];
    const float* b2   = (const float*)d_in[9];
    float* out = (float*)d_out;

    char* w = (char*)d_ws;
    size_t off = 0;
    auto alloc = [&](size_t bytes) -> void* {
        void* p = w + off;
        off = (off + bytes + 255) & ~(size_t)255;
        return p;
    };
    uint* xlh2   = (uint*)alloc((size_t)NN * 32 * 4);
    uint* xrh2   = (uint*)alloc((size_t)NN * 32 * 4);
    uint* hbh2   = (uint*)alloc((size_t)NN * 32 * 4);
    uint* xl2h   = (uint*)alloc((size_t)NN * 8 * 4);
    uint* xr2h   = (uint*)alloc((size_t)NN * 8 * 4);
    uint* temp   = (uint*)alloc((size_t)P1B * CHUNK * 4);
    int*  lbmat  = (int*)alloc((size_t)P1B * LBW * 4);
    int*  rowptr = (int*)alloc((size_t)NN * 4);
    int*  deg    = (int*)alloc((size_t)NN * 4);
    int*  csr_src = (int*)alloc((size_t)(NE + 64) * 4);

    k_fusedA<<<P1B + 2 * G1T, 256, 0, stream>>>(x, ei, W1l, W1r, xlh2, xrh2, temp, lbmat);
    k_pass2<<<NB, 256, 0, stream>>>(temp, lbmat, rowptr, deg, csr_src);
    k_agg1<<<(NN + 3) / 4, 256, 0, stream>>>(xlh2, xrh2, rowptr, deg, csr_src, att1, b1, hbh2);
    k_gemm2<<<(NN + 255) / 256, 256, 0, stream>>>(hbh2, W2l, W2r, xl2h, xr2h);
    k_agg2<<<(NN + 3) / 4, 256, 0, stream>>>(xl2h, xr2h, rowptr, deg, csr_src, att2, b2, out);
}

// Round 11
// 106.920 us; speedup vs baseline: 1.1389x; 1.0367x over previous
//
#include <hip/hip_runtime.h>
#include <math.h>

#define NN 50000
#define NE 800000
#define FIN 128
#define NC 10
#define NEG 0.2f
#define LOG2E 1.4426950408889634f

#define NB 196        // coarse buckets = ceil(NN/256), bucket = dst>>8
#define CHUNK 4096    // edges per pass1 block
#define P1B ((NE + CHUNK - 1) / CHUNK)   // 196
#define CAP 5120      // LDS capacity for one bucket in pass2
#define G1T ((NN + 127) / 128)           // 391 gemm1 tiles (128 nodes each)
#define LBW 200       // lbmat row stride

typedef unsigned int uint;
typedef unsigned char uchar;
typedef _Float16 h2 __attribute__((ext_vector_type(2)));
typedef __fp16 hb2 __attribute__((ext_vector_type(2)));
union U2H { uint u; h2 h; };

__device__ __forceinline__ uint pkrtz_u(float a, float b) {
    union { hb2 f; uint u; } r;
    r.f = __builtin_amdgcn_cvt_pkrtz(a, b);
    return r.u;
}

__device__ __forceinline__ float dot2f(h2 a, h2 b, float c) {
#if __has_builtin(__builtin_amdgcn_fdot2)
    return __builtin_amdgcn_fdot2(a, b, c, false);
#else
    return fmaf((float)a.x, (float)b.x, fmaf((float)a.y, (float)b.y, c));
#endif
}

__device__ __forceinline__ h2 lrelu2(h2 v) {
    return __builtin_elementwise_max(v, v * (_Float16)0.2f);
}

template<int CTRL>
__device__ __forceinline__ float dpp_add(float x) {
    int y = __builtin_amdgcn_update_dpp(0, __float_as_int(x), CTRL, 0xF, 0xF, true);
    return x + __int_as_float(y);
}
// sum over aligned 8-lane groups (= one head's 16 channels in half2 layout)
__device__ __forceinline__ float red8(float t) {
    t = dpp_add<0xB1>(t);
    t = dpp_add<0x4E>(t);
    t = dpp_add<0x141>(t);
    return t;
}

__device__ __forceinline__ int excl_scan256(int v, int* sc) {
    const int t = threadIdx.x;
    sc[t] = v;
    __syncthreads();
    for (int o = 1; o < 256; o <<= 1) {
        int u = (t >= o) ? sc[t - o] : 0;
        __syncthreads();
        sc[t] += u;
        __syncthreads();
    }
    return sc[t] - v;
}

// ---------------- fused kernel A: pass1 bucket-sort (deterministic) || gemm1(f16) ----------------

__device__ void pass1_body(const int* __restrict__ ei, uint* __restrict__ temp,
                           int* __restrict__ lbmat, char* smraw) {
    uint* pk = (uint*)smraw;                  // 16384 B [4096]
    int* h   = (int*)(smraw + 16384);         // 1024
    int* h2_ = (int*)(smraw + 17408);         // 1024
    int* sc  = (int*)(smraw + 18432);         // 1024
    const int t = threadIdx.x;
    const int B = blockIdx.x;
    const int e0 = B * CHUNK;
    const int cnt = min(CHUNK, NE - e0);

    h[t] = 0; h2_[t] = 0;
    __syncthreads();
    for (int i = t; i < cnt; i += 256) {
        int d = ei[NE + e0 + i];
        atomicAdd(&h[d >> 8], 1);
    }
    __syncthreads();
    const int hv = h[t];
    const int ex = excl_scan256(hv, sc);
    if (t < NB) lbmat[B * LBW + t] = ex;
    if (t == NB - 1) lbmat[B * LBW + NB] = ex + hv;   // = cnt
    h2_[t] = ex;
    __syncthreads();
    for (int i = t; i < cnt; i += 256) {
        int s = ei[e0 + i];
        int d = ei[NE + e0 + i];
        int b = d >> 8;
        int pos = atomicAdd(&h2_[b], 1);
        pk[pos] = ((uint)s << 8) | ((uint)d & 255u);
    }
    __syncthreads();
    for (int i = t; i < cnt; i += 256) temp[B * CHUNK + i] = pk[i];
}

// gemm1: tile 128 nodes x 64 cols, thread = 8 nodes x 4 cols (f16 dot2) — R7-proven
__device__ void gemm1_body(const float* __restrict__ x, const float* __restrict__ W,
                           uint* __restrict__ oh2, int n0, char* smraw) {
    uint (*Wsh)[64]  = (uint(*)[64])smraw;             // [64 kp][64 col] 16KB
    uint (*xTh)[128] = (uint(*)[128])(smraw + 16384);  // [16 kp][128 node] 8KB
    const int t = threadIdx.x;

    for (int i = t; i < 4096; i += 256) {   // stage W as k-paired half2
        int kp = i >> 6, col = i & 63;
        Wsh[kp][col] = pkrtz_u(W[(2 * kp) * 64 + col], W[(2 * kp + 1) * 64 + col]);
    }

    const int tn = t >> 4;          // node group: nodes tn*8..+7
    const int tc = t & 15;          // col group : cols tc*4..+3
    float acc[8][4] = {};
    const int sn = t >> 1;          // staging node 0..127
    const int kp0 = (t & 1) * 8;    // staging k-pair offset within chunk

    for (int kc = 0; kc < FIN; kc += 32) {
        __syncthreads();
        {
            int gn = n0 + sn;
            float4 v0, v1, v2, v3;
            if (gn < NN) {
                const float4* xr_ = (const float4*)(x + (size_t)gn * FIN + kc + kp0 * 2);
                v0 = xr_[0]; v1 = xr_[1]; v2 = xr_[2]; v3 = xr_[3];
            } else {
                v0 = v1 = v2 = v3 = make_float4(0.f, 0.f, 0.f, 0.f);
            }
            xTh[kp0 + 0][sn] = pkrtz_u(v0.x, v0.y);
            xTh[kp0 + 1][sn] = pkrtz_u(v0.z, v0.w);
            xTh[kp0 + 2][sn] = pkrtz_u(v1.x, v1.y);
            xTh[kp0 + 3][sn] = pkrtz_u(v1.z, v1.w);
            xTh[kp0 + 4][sn] = pkrtz_u(v2.x, v2.y);
            xTh[kp0 + 5][sn] = pkrtz_u(v2.z, v2.w);
            xTh[kp0 + 6][sn] = pkrtz_u(v3.x, v3.y);
            xTh[kp0 + 7][sn] = pkrtz_u(v3.z, v3.w);
        }
        __syncthreads();
        const int kpc = kc >> 1;
#pragma unroll
        for (int kp = 0; kp < 16; ++kp) {
            uint4 wv = *(const uint4*)&Wsh[kpc + kp][tc * 4];
            uint4 xa = *(const uint4*)&xTh[kp][tn * 8];
            uint4 xb = *(const uint4*)&xTh[kp][tn * 8 + 4];
            U2H w0, w1, w2, w3, x0, x1, x2, x3, x4, x5, x6, x7;
            w0.u = wv.x; w1.u = wv.y; w2.u = wv.z; w3.u = wv.w;
            x0.u = xa.x; x1.u = xa.y; x2.u = xa.z; x3.u = xa.w;
            x4.u = xb.x; x5.u = xb.y; x6.u = xb.z; x7.u = xb.w;
            h2 xs[8] = {x0.h, x1.h, x2.h, x3.h, x4.h, x5.h, x6.h, x7.h};
#pragma unroll
            for (int i = 0; i < 8; ++i) {
                acc[i][0] = dot2f(xs[i], w0.h, acc[i][0]);
                acc[i][1] = dot2f(xs[i], w1.h, acc[i][1]);
                acc[i][2] = dot2f(xs[i], w2.h, acc[i][2]);
                acc[i][3] = dot2f(xs[i], w3.h, acc[i][3]);
            }
        }
    }
#pragma unroll
    for (int i = 0; i < 8; ++i) {
        int n = n0 + tn * 8 + i;
        if (n < NN) {
            uint p0 = pkrtz_u(acc[i][0], acc[i][1]);
            uint p1 = pkrtz_u(acc[i][2], acc[i][3]);
            *(uint2*)&oh2[(size_t)n * 32 + tc * 2] = make_uint2(p0, p1);
        }
    }
}

__global__ __launch_bounds__(256) void k_fusedA(const float* __restrict__ x,
                                                const int* __restrict__ ei,
                                                const float* __restrict__ W1l,
                                                const float* __restrict__ W1r,
                                                uint* __restrict__ xlh2,
                                                uint* __restrict__ xrh2,
                                                uint* __restrict__ temp,
                                                int* __restrict__ lbmat) {
    __shared__ __align__(16) char smraw[25600];
    if (blockIdx.x < P1B) {
        pass1_body(ei, temp, lbmat, smraw);
    } else {
        int g = blockIdx.x - P1B;
        bool left = g < G1T;
        int n0 = (left ? g : g - G1T) * 128;
        gemm1_body(x, left ? W1l : W1r, left ? xlh2 : xrh2, n0, smraw);
    }
}

// ---------------- pass2: pull-based per-bucket CSR (no global atomics) ----------------

__global__ __launch_bounds__(256) void k_pass2(const uint* __restrict__ temp,
                                               const int* __restrict__ lbmat,
                                               int* __restrict__ rowptr,
                                               int* __restrict__ deg,
                                               int* __restrict__ csr_src) {
    __shared__ uint P[CAP];
    __shared__ int nh[256], nbx[256], ncur[256], sc[256];
    const int t = threadIdx.x;
    const int b = blockIdx.x;

    int lbv = 0, len = 0;
    if (t < P1B) {
        lbv = lbmat[t * LBW + b];
        len = lbmat[t * LBW + b + 1] - lbv;
    }
    const int colstart = excl_scan256(len, sc);
    __syncthreads();
    const int cnt = sc[255];
    __syncthreads();
    (void)excl_scan256(lbv, sc);
    __syncthreads();
    const int csrbase = sc[255];
    __syncthreads();
    nh[t] = 0; ncur[t] = 0;
    __syncthreads();
    if (t < P1B) {
        const uint* src = temp + t * CHUNK + lbv;
        for (int i = 0; i < len; ++i) P[colstart + i] = src[i];
    }
    __syncthreads();
    for (int i = t; i < cnt; i += 256) atomicAdd(&nh[P[i] & 255u], 1);
    __syncthreads();
    const int c = nh[t];
    const int nb_ex = excl_scan256(c, sc);
    nbx[t] = nb_ex;
    const int gnode = b * 256 + t;
    if (gnode < NN) { rowptr[gnode] = csrbase + nb_ex; deg[gnode] = c; }
    __syncthreads();
    for (int i = t; i < cnt; i += 256) {
        uint v = P[i];
        int l = (int)(v & 255u);
        int r = atomicAdd(&ncur[l], 1);
        csr_src[csrbase + nbx[l] + r] = (int)(v >> 8);
    }
}

// ---------------- layer 1 aggregate: masked batch-4, exp2 ----------------

__global__ __launch_bounds__(256) void k_agg1(const uint* __restrict__ xlh2,
                                              const uint* __restrict__ xrh2,
                                              const int* __restrict__ rowptr,
                                              const int* __restrict__ deg,
                                              const int* __restrict__ csr_src,
                                              const float* __restrict__ att1,
                                              const float* __restrict__ b1,
                                              uint* __restrict__ hbh2) {
    const int node = blockIdx.x * 4 + (threadIdx.x >> 6);
    if (node >= NN) return;
    const int lane = threadIdx.x & 63;
    const int fl = lane & 31;        // feature-pair
    const int hid = lane >> 5;       // edge-half id
    float2 av = *(const float2*)&att1[2 * fl];
    U2H att; att.u = pkrtz_u(av.x * LOG2E, av.y * LOG2E);  // fold log2e -> exp2
    U2H xrf; xrf.u = xrh2[(size_t)node * 32 + fl];
    const int start = rowptr[node];
    const int dg = deg[node];
    const int permbase = (lane & 32) >> 3;   // 0 or 4

    float denom = 0.f, acc0 = 0.f, acc1 = 0.f;
    for (int base = 0; base < dg; base += 64) {
        int idx = base + lane;
        int srcs = (idx < dg) ? csr_src[start + idx] : 0;
        int rem = dg - base; if (rem > 64) rem = 64;
        int iters = (rem + 1) >> 1;
        int thr = (rem - hid + 1) >> 1;      // edge (2j+hid) valid iff j < thr
        for (int jj = 0; jj < iters; jj += 4) {
            // OOB bpermute wraps to a valid lane -> valid node id; e=0 masks it
            int s0 = __builtin_amdgcn_ds_bpermute((jj + 0) * 8 + permbase, srcs);
            int s1 = __builtin_amdgcn_ds_bpermute((jj + 1) * 8 + permbase, srcs);
            int s2 = __builtin_amdgcn_ds_bpermute((jj + 2) * 8 + permbase, srcs);
            int s3 = __builtin_amdgcn_ds_bpermute((jj + 3) * 8 + permbase, srcs);
            U2H v0; v0.u = xlh2[(size_t)s0 * 32 + fl];
            U2H v1; v1.u = xlh2[(size_t)s1 * 32 + fl];
            U2H v2; v2.u = xlh2[(size_t)s2 * 32 + fl];
            U2H v3; v3.u = xlh2[(size_t)s3 * 32 + fl];
            float t0 = red8(dot2f(lrelu2(v0.h + xrf.h), att.h, 0.f));
            float t1 = red8(dot2f(lrelu2(v1.h + xrf.h), att.h, 0.f));
            float t2 = red8(dot2f(lrelu2(v2.h + xrf.h), att.h, 0.f));
            float t3 = red8(dot2f(lrelu2(v3.h + xrf.h), att.h, 0.f));
            float e0 = (jj + 0 < thr) ? exp2f(t0) : 0.f;
            float e1 = (jj + 1 < thr) ? exp2f(t1) : 0.f;
            float e2 = (jj + 2 < thr) ? exp2f(t2) : 0.f;
            float e3 = (jj + 3 < thr) ? exp2f(t3) : 0.f;
            denom += (e0 + e1) + (e2 + e3);
            acc0 = fmaf(e0, (float)v0.h.x, acc0);
            acc0 = fmaf(e1, (float)v1.h.x, acc0);
            acc0 = fmaf(e2, (float)v2.h.x, acc0);
            acc0 = fmaf(e3, (float)v3.h.x, acc0);
            acc1 = fmaf(e0, (float)v0.h.y, acc1);
            acc1 = fmaf(e1, (float)v1.h.y, acc1);
            acc1 = fmaf(e2, (float)v2.h.y, acc1);
            acc1 = fmaf(e3, (float)v3.h.y, acc1);
        }
    }
    denom += __shfl_xor(denom, 32);
    acc0  += __shfl_xor(acc0, 32);
    acc1  += __shfl_xor(acc1, 32);
    if (lane < 32) {
        float r = (dg > 0) ? (1.0f / denom) : 0.f;
        float2 bv = *(const float2*)&b1[2 * fl];
        float o0 = fmaf(acc0, r, bv.x);
        float o1 = fmaf(acc1, r, bv.y);
        o0 = o0 > 0.f ? o0 : expm1f(o0);
        o1 = o1 > 0.f ? o1 : expm1f(o1);
        hbh2[(size_t)node * 32 + fl] = pkrtz_u(o0, o1);
    }
}

// ---------------- layer 2 GEMM: node per thread, packed half2 outputs ----------------

__global__ __launch_bounds__(256) void k_gemm2(const uint* __restrict__ hbh2,
                                               const float* __restrict__ W2l,
                                               const float* __restrict__ W2r,
                                               uint* __restrict__ xl2h,
                                               uint* __restrict__ xr2h) {
    int n = blockIdx.x * 256 + threadIdx.x;
    if (n >= NN) return;
    float al[NC] = {}, ar[NC] = {};
    const uint4* hr4 = (const uint4*)(hbh2 + (size_t)n * 32);
#pragma unroll
    for (int q = 0; q < 8; ++q) {
        uint4 qq = hr4[q];
        uint uu[4] = {qq.x, qq.y, qq.z, qq.w};
#pragma unroll
        for (int j = 0; j < 4; ++j) {
            U2H hh; hh.u = uu[j];
            float f0 = (float)hh.h.x, f1 = (float)hh.h.y;
            int k = q * 8 + j * 2;
            const float* wl0 = W2l + k * NC;
            const float* wr0 = W2r + k * NC;
#pragma unroll
            for (int c = 0; c < NC; ++c) {
                al[c] = fmaf(f0, wl0[c], fmaf(f1, wl0[NC + c], al[c]));
                ar[c] = fmaf(f0, wr0[c], fmaf(f1, wr0[NC + c], ar[c]));
            }
        }
    }
    uint p0 = pkrtz_u(al[0], al[1]);
    uint p1 = pkrtz_u(al[2], al[3]);
    uint p2 = pkrtz_u(al[4], al[5]);
    uint p3 = pkrtz_u(al[6], al[7]);
    uint p4 = pkrtz_u(al[8], al[9]);
    *(uint4*)&xl2h[(size_t)n * 8]     = make_uint4(p0, p1, p2, p3);
    *(uint4*)&xl2h[(size_t)n * 8 + 4] = make_uint4(p4, 0u, 0u, 0u);
    p0 = pkrtz_u(ar[0], ar[1]);
    p1 = pkrtz_u(ar[2], ar[3]);
    p2 = pkrtz_u(ar[4], ar[5]);
    p3 = pkrtz_u(ar[6], ar[7]);
    p4 = pkrtz_u(ar[8], ar[9]);
    *(uint4*)&xr2h[(size_t)n * 8]     = make_uint4(p0, p1, p2, p3);
    *(uint4*)&xr2h[(size_t)n * 8 + 4] = make_uint4(p4, 0u, 0u, 0u);
}

// ---------------- layer 2 aggregate: masked batch-4, exp2 ----------------

__global__ __launch_bounds__(256) void k_agg2(const uint* __restrict__ xl2h,
                                              const uint* __restrict__ xr2h,
                                              const int* __restrict__ rowptr,
                                              const int* __restrict__ deg,
                                              const int* __restrict__ csr_src,
                                              const float* __restrict__ att2,
                                              const float* __restrict__ b2,
                                              float* __restrict__ out) {
    const int node = blockIdx.x * 4 + (threadIdx.x >> 6);
    if (node >= NN) return;
    const int lane = threadIdx.x & 63;
    const int fp = lane & 7;         // feature-pair (0..4 real, 5..7 pad)
    const int eg = lane >> 3;        // edge group 0..7
    U2H att;
    if (fp < 5) {
        float2 av = *(const float2*)&att2[2 * fp];
        att.u = pkrtz_u(av.x * LOG2E, av.y * LOG2E);
    } else {
        att.u = 0;
    }
    U2H xrf; xrf.u = xr2h[(size_t)node * 8 + fp];
    const int start = rowptr[node];
    const int dg = deg[node];
    const int permbase = eg * 4;

    float denom = 0.f, acc0 = 0.f, acc1 = 0.f;
    for (int base = 0; base < dg; base += 64) {
        int idx = base + lane;
        int srcs = (idx < dg) ? csr_src[start + idx] : 0;
        int rem = dg - base; if (rem > 64) rem = 64;
        int iters = (rem + 7) >> 3;
        int thr = (rem - eg + 7) >> 3;
        for (int jj = 0; jj < iters; jj += 4) {
            int s[4]; U2H v[4];
#pragma unroll
            for (int k = 0; k < 4; ++k)
                s[k] = __builtin_amdgcn_ds_bpermute((jj + k) * 32 + permbase, srcs);
#pragma unroll
            for (int k = 0; k < 4; ++k)
                v[k].u = xl2h[(size_t)s[k] * 8 + fp];
#pragma unroll
            for (int k = 0; k < 4; ++k) {
                float tl = red8(dot2f(lrelu2(v[k].h + xrf.h), att.h, 0.f));
                float e = (jj + k < thr) ? exp2f(tl) : 0.f;
                denom += e;
                acc0 = fmaf(e, (float)v[k].h.x, acc0);
                acc1 = fmaf(e, (float)v[k].h.y, acc1);
            }
        }
    }
#pragma unroll
    for (int m = 8; m <= 32; m <<= 1) {
        denom += __shfl_xor(denom, m);
        acc0  += __shfl_xor(acc0, m);
        acc1  += __shfl_xor(acc1, m);
    }
    if (lane < 5) {
        float r = (dg > 0) ? (1.0f / denom) : 0.f;
        float2 o;
        o.x = fmaf(acc0, r, b2[2 * fp]);
        o.y = fmaf(acc1, r, b2[2 * fp + 1]);
        *(float2*)&out[(size_t)node * NC + 2 * fp] = o;
    }
}

// ---------------- launch ----------------

extern "C" void kernel_launch(void* const* d_in, const int* in_sizes, int n_in,
                              void* d_out, int out_size, void* d_ws, size_t ws_size,
                              hipStream_t stream) {
    const float* x    = (const float*)d_in[0];
    const int*   ei   = (const int*)d_in[1];
    const float* W1l  = (const float*)d_in[2];
    const float* W1r  = (const float*)d_in[3];
    const float* att1 = (const float*)d_in[4];
    const float* b1   = (const float*)d_in[5];
    const float* W2l  = (const float*)d_in[6];
    const float* W2r  = (const float*)d_in[7];
    const float* att2 = (const float*)d_in[8];
    const float* b2   = (const float*)d_in[9];
    float* out = (float*)d_out;

    char* w = (char*)d_ws;
    size_t off = 0;
    auto alloc = [&](size_t bytes) -> void* {
        void* p = w + off;
        off = (off + bytes + 255) & ~(size_t)255;
        return p;
    };
    uint* xlh2   = (uint*)alloc((size_t)NN * 32 * 4);
    uint* xrh2   = (uint*)alloc((size_t)NN * 32 * 4);
    uint* hbh2   = (uint*)alloc((size_t)NN * 32 * 4);
    uint* xl2h   = (uint*)alloc((size_t)NN * 8 * 4);
    uint* xr2h   = (uint*)alloc((size_t)NN * 8 * 4);
    uint* temp   = (uint*)alloc((size_t)P1B * CHUNK * 4);
    int*  lbmat  = (int*)alloc((size_t)P1B * LBW * 4);
    int*  rowptr = (int*)alloc((size_t)NN * 4);
    int*  deg    = (int*)alloc((size_t)NN * 4);
    int*  csr_src = (int*)alloc((size_t)(NE + 64) * 4);

    k_fusedA<<<P1B + 2 * G1T, 256, 0, stream>>>(x, ei, W1l, W1r, xlh2, xrh2, temp, lbmat);
    k_pass2<<<NB, 256, 0, stream>>>(temp, lbmat, rowptr, deg, csr_src);
    k_agg1<<<(NN + 3) / 4, 256, 0, stream>>>(xlh2, xrh2, rowptr, deg, csr_src, att1, b1, hbh2);
    k_gemm2<<<(NN + 255) / 256, 256, 0, stream>>>(hbh2, W2l, W2r, xl2h, xr2h);
    k_agg2<<<(NN + 3) / 4, 256, 0, stream>>>(xl2h, xr2h, rowptr, deg, csr_src, att2, b2, out);
}

// Round 12
// 97.060 us; speedup vs baseline: 1.2546x; 1.1016x over previous
//
#include <hip/hip_runtime.h>
#include <math.h>

#define NN 50000
#define NE 800000
#define FIN 128
#define NC 10
#define NEG 0.2f
#define LOG2E 1.4426950408889634f

#define NB 196        // coarse buckets = ceil(NN/256), bucket = dst>>8
#define CHUNK 4096    // edges per pass1 block
#define P1B ((NE + CHUNK - 1) / CHUNK)   // 196
#define CAP 5120      // LDS capacity for one bucket in pass2
#define GMT ((NN + 63) / 64)             // 782 mfma-gemm tiles (64 nodes, both W)
#define LBW 200       // lbmat row stride
#define WPAD 136      // Wt row stride in f16 (272B: 16B-aligned, bank-balanced)

typedef unsigned int uint;
typedef _Float16 h2 __attribute__((ext_vector_type(2)));
typedef _Float16 h8 __attribute__((ext_vector_type(8)));
typedef float f32x4 __attribute__((ext_vector_type(4)));
typedef __fp16 hb2 __attribute__((ext_vector_type(2)));
union U2H { uint u; h2 h; };
union U4H8 { uint4 u; h8 h; };

__device__ __forceinline__ uint pkrtz_u(float a, float b) {
    union { hb2 f; uint u; } r;
    r.f = __builtin_amdgcn_cvt_pkrtz(a, b);
    return r.u;
}

__device__ __forceinline__ float dot2f(h2 a, h2 b, float c) {
#if __has_builtin(__builtin_amdgcn_fdot2)
    return __builtin_amdgcn_fdot2(a, b, c, false);
#else
    return fmaf((float)a.x, (float)b.x, fmaf((float)a.y, (float)b.y, c));
#endif
}

__device__ __forceinline__ h2 lrelu2(h2 v) {
    return __builtin_elementwise_max(v, v * (_Float16)0.2f);
}

template<int CTRL>
__device__ __forceinline__ float dpp_add(float x) {
    int y = __builtin_amdgcn_update_dpp(0, __float_as_int(x), CTRL, 0xF, 0xF, true);
    return x + __int_as_float(y);
}
__device__ __forceinline__ float red8(float t) {
    t = dpp_add<0xB1>(t);
    t = dpp_add<0x4E>(t);
    t = dpp_add<0x141>(t);
    return t;
}

__device__ __forceinline__ int excl_scan256(int v, int* sc) {
    const int t = threadIdx.x;
    sc[t] = v;
    __syncthreads();
    for (int o = 1; o < 256; o <<= 1) {
        int u = (t >= o) ? sc[t - o] : 0;
        __syncthreads();
        sc[t] += u;
        __syncthreads();
    }
    return sc[t] - v;
}

// ---------------- fused kernel A: pass1 bucket-sort || gemm1 (MFMA f16) ----------------

__device__ void pass1_body(const int* __restrict__ ei, uint* __restrict__ temp,
                           int* __restrict__ lbmat, char* smraw) {
    uint* pk = (uint*)smraw;                  // 16384 B [4096]
    int* h   = (int*)(smraw + 16384);         // 1024
    int* h2_ = (int*)(smraw + 17408);         // 1024
    int* sc  = (int*)(smraw + 18432);         // 1024
    const int t = threadIdx.x;
    const int B = blockIdx.x;
    const int e0 = B * CHUNK;
    const int cnt = min(CHUNK, NE - e0);

    h[t] = 0; h2_[t] = 0;
    __syncthreads();
    for (int i = t; i < cnt; i += 256) {
        int d = ei[NE + e0 + i];
        atomicAdd(&h[d >> 8], 1);
    }
    __syncthreads();
    const int hv = h[t];
    const int ex = excl_scan256(hv, sc);
    if (t < NB) lbmat[B * LBW + t] = ex;
    if (t == NB - 1) lbmat[B * LBW + NB] = ex + hv;
    h2_[t] = ex;
    __syncthreads();
    for (int i = t; i < cnt; i += 256) {
        int s = ei[e0 + i];
        int d = ei[NE + e0 + i];
        int b = d >> 8;
        int pos = atomicAdd(&h2_[b], 1);
        pk[pos] = ((uint)s << 8) | ((uint)d & 255u);
    }
    __syncthreads();
    for (int i = t; i < cnt; i += 256) temp[B * CHUNK + i] = pk[i];
}

// gemm1 MFMA: block = 64 nodes x 128 cols (both W sides). 4 waves x 16 nodes.
// A (x-tile) loaded from global per-lane (row=lane&15, k=8*(lane>>4)+j);
// B from LDS-transposed Wt[col][k]; C/D: col=lane&15, row=(lane>>4)*4+reg.
__device__ void gemm1_body(const float* __restrict__ x,
                           const float* __restrict__ W1l,
                           const float* __restrict__ W1r,
                           _Float16* __restrict__ xlh,
                           _Float16* __restrict__ xrh,
                           int n0, char* smraw) {
    _Float16 (*WtL)[WPAD] = (_Float16(*)[WPAD])smraw;
    _Float16 (*WtR)[WPAD] = (_Float16(*)[WPAD])(smraw + 64 * WPAD * 2);
    const int t = threadIdx.x;

    for (int i = t; i < FIN * 64; i += 256) {   // stage both W transposed as f16
        int k = i >> 6, c = i & 63;
        WtL[c][k] = (_Float16)W1l[i];
        WtR[c][k] = (_Float16)W1r[i];
    }
    __syncthreads();

    const int lane = t & 63;
    const int n0w = n0 + (t >> 6) * 16;      // this wave's 16-node tile
    const int arow = n0w + (lane & 15);
    const int kgrp = (lane >> 4) * 8;        // lane's 8-k group offset
    const int col16 = lane & 15;

    f32x4 acc[8] = {};
    for (int kk = 0; kk < FIN; kk += 32) {
        U4H8 a;
        if (arow < NN) {
            const float4* xp = (const float4*)(x + (size_t)arow * FIN + kk + kgrp);
            float4 v0 = xp[0], v1 = xp[1];
            a.u = make_uint4(pkrtz_u(v0.x, v0.y), pkrtz_u(v0.z, v0.w),
                             pkrtz_u(v1.x, v1.y), pkrtz_u(v1.z, v1.w));
        } else {
            a.u = make_uint4(0u, 0u, 0u, 0u);
        }
        const int kof = kk + kgrp;
#pragma unroll
        for (int ct = 0; ct < 4; ++ct) {
            U4H8 b; b.u = *(const uint4*)&WtL[ct * 16 + col16][kof];
            acc[ct] = __builtin_amdgcn_mfma_f32_16x16x32_f16(a.h, b.h, acc[ct], 0, 0, 0);
        }
#pragma unroll
        for (int ct = 0; ct < 4; ++ct) {
            U4H8 b; b.u = *(const uint4*)&WtR[ct * 16 + col16][kof];
            acc[4 + ct] = __builtin_amdgcn_mfma_f32_16x16x32_f16(a.h, b.h, acc[4 + ct], 0, 0, 0);
        }
    }
    const int crow0 = n0w + (lane >> 4) * 4;
#pragma unroll
    for (int ct = 0; ct < 8; ++ct) {
        _Float16* __restrict__ op = (ct < 4) ? xlh : xrh;
        const int col = (ct & 3) * 16 + col16;
#pragma unroll
        for (int r = 0; r < 4; ++r) {
            int node = crow0 + r;
            if (node < NN) op[(size_t)node * 64 + col] = (_Float16)acc[ct][r];
        }
    }
}

__global__ __launch_bounds__(256) void k_fusedA(const float* __restrict__ x,
                                                const int* __restrict__ ei,
                                                const float* __restrict__ W1l,
                                                const float* __restrict__ W1r,
                                                _Float16* __restrict__ xlh,
                                                _Float16* __restrict__ xrh,
                                                uint* __restrict__ temp,
                                                int* __restrict__ lbmat) {
    __shared__ __align__(16) char smraw[64 * WPAD * 2 * 2];   // 34816 B
    if (blockIdx.x < P1B) {
        pass1_body(ei, temp, lbmat, smraw);
    } else {
        int g = blockIdx.x - P1B;
        gemm1_body(x, W1l, W1r, xlh, xrh, g * 64, smraw);
    }
}

// ---------------- pass2: pull-based per-bucket CSR (no global atomics) ----------------

__global__ __launch_bounds__(256) void k_pass2(const uint* __restrict__ temp,
                                               const int* __restrict__ lbmat,
                                               int* __restrict__ rowptr,
                                               int* __restrict__ deg,
                                               int* __restrict__ csr_src) {
    __shared__ uint P[CAP];
    __shared__ int nh[256], nbx[256], ncur[256], sc[256];
    const int t = threadIdx.x;
    const int b = blockIdx.x;

    int lbv = 0, len = 0;
    if (t < P1B) {
        lbv = lbmat[t * LBW + b];
        len = lbmat[t * LBW + b + 1] - lbv;
    }
    const int colstart = excl_scan256(len, sc);
    __syncthreads();
    const int cnt = sc[255];
    __syncthreads();
    (void)excl_scan256(lbv, sc);
    __syncthreads();
    const int csrbase = sc[255];
    __syncthreads();
    nh[t] = 0; ncur[t] = 0;
    __syncthreads();
    if (t < P1B) {
        const uint* src = temp + t * CHUNK + lbv;
        for (int i = 0; i < len; ++i) P[colstart + i] = src[i];
    }
    __syncthreads();
    for (int i = t; i < cnt; i += 256) atomicAdd(&nh[P[i] & 255u], 1);
    __syncthreads();
    const int c = nh[t];
    const int nb_ex = excl_scan256(c, sc);
    nbx[t] = nb_ex;
    const int gnode = b * 256 + t;
    if (gnode < NN) { rowptr[gnode] = csrbase + nb_ex; deg[gnode] = c; }
    __syncthreads();
    for (int i = t; i < cnt; i += 256) {
        uint v = P[i];
        int l = (int)(v & 255u);
        int r = atomicAdd(&ncur[l], 1);
        csr_src[csrbase + nbx[l] + r] = (int)(v >> 8);
    }
}

// ---------------- layer 1 aggregate: masked batch-4, exp2 (frozen from R11) ----------------

__global__ __launch_bounds__(256) void k_agg1(const uint* __restrict__ xlh2,
                                              const uint* __restrict__ xrh2,
                                              const int* __restrict__ rowptr,
                                              const int* __restrict__ deg,
                                              const int* __restrict__ csr_src,
                                              const float* __restrict__ att1,
                                              const float* __restrict__ b1,
                                              uint* __restrict__ hbh2) {
    const int node = blockIdx.x * 4 + (threadIdx.x >> 6);
    if (node >= NN) return;
    const int lane = threadIdx.x & 63;
    const int fl = lane & 31;
    const int hid = lane >> 5;
    float2 av = *(const float2*)&att1[2 * fl];
    U2H att; att.u = pkrtz_u(av.x * LOG2E, av.y * LOG2E);
    U2H xrf; xrf.u = xrh2[(size_t)node * 32 + fl];
    const int start = rowptr[node];
    const int dg = deg[node];
    const int permbase = (lane & 32) >> 3;

    float denom = 0.f, acc0 = 0.f, acc1 = 0.f;
    for (int base = 0; base < dg; base += 64) {
        int idx = base + lane;
        int srcs = (idx < dg) ? csr_src[start + idx] : 0;
        int rem = dg - base; if (rem > 64) rem = 64;
        int iters = (rem + 1) >> 1;
        int thr = (rem - hid + 1) >> 1;
        for (int jj = 0; jj < iters; jj += 4) {
            int s0 = __builtin_amdgcn_ds_bpermute((jj + 0) * 8 + permbase, srcs);
            int s1 = __builtin_amdgcn_ds_bpermute((jj + 1) * 8 + permbase, srcs);
            int s2 = __builtin_amdgcn_ds_bpermute((jj + 2) * 8 + permbase, srcs);
            int s3 = __builtin_amdgcn_ds_bpermute((jj + 3) * 8 + permbase, srcs);
            U2H v0; v0.u = xlh2[(size_t)s0 * 32 + fl];
            U2H v1; v1.u = xlh2[(size_t)s1 * 32 + fl];
            U2H v2; v2.u = xlh2[(size_t)s2 * 32 + fl];
            U2H v3; v3.u = xlh2[(size_t)s3 * 32 + fl];
            float t0 = red8(dot2f(lrelu2(v0.h + xrf.h), att.h, 0.f));
            float t1 = red8(dot2f(lrelu2(v1.h + xrf.h), att.h, 0.f));
            float t2 = red8(dot2f(lrelu2(v2.h + xrf.h), att.h, 0.f));
            float t3 = red8(dot2f(lrelu2(v3.h + xrf.h), att.h, 0.f));
            float e0 = (jj + 0 < thr) ? exp2f(t0) : 0.f;
            float e1 = (jj + 1 < thr) ? exp2f(t1) : 0.f;
            float e2 = (jj + 2 < thr) ? exp2f(t2) : 0.f;
            float e3 = (jj + 3 < thr) ? exp2f(t3) : 0.f;
            denom += (e0 + e1) + (e2 + e3);
            acc0 = fmaf(e0, (float)v0.h.x, acc0);
            acc0 = fmaf(e1, (float)v1.h.x, acc0);
            acc0 = fmaf(e2, (float)v2.h.x, acc0);
            acc0 = fmaf(e3, (float)v3.h.x, acc0);
            acc1 = fmaf(e0, (float)v0.h.y, acc1);
            acc1 = fmaf(e1, (float)v1.h.y, acc1);
            acc1 = fmaf(e2, (float)v2.h.y, acc1);
            acc1 = fmaf(e3, (float)v3.h.y, acc1);
        }
    }
    denom += __shfl_xor(denom, 32);
    acc0  += __shfl_xor(acc0, 32);
    acc1  += __shfl_xor(acc1, 32);
    if (lane < 32) {
        float r = (dg > 0) ? (1.0f / denom) : 0.f;
        float2 bv = *(const float2*)&b1[2 * fl];
        float o0 = fmaf(acc0, r, bv.x);
        float o1 = fmaf(acc1, r, bv.y);
        o0 = o0 > 0.f ? o0 : expm1f(o0);
        o1 = o1 > 0.f ? o1 : expm1f(o1);
        hbh2[(size_t)node * 32 + fl] = pkrtz_u(o0, o1);
    }
}

// ---------------- layer 2 GEMM: node per thread, packed half2 outputs ----------------

__global__ __launch_bounds__(256) void k_gemm2(const uint* __restrict__ hbh2,
                                               const float* __restrict__ W2l,
                                               const float* __restrict__ W2r,
                                               uint* __restrict__ xl2h,
                                               uint* __restrict__ xr2h) {
    int n = blockIdx.x * 256 + threadIdx.x;
    if (n >= NN) return;
    float al[NC] = {}, ar[NC] = {};
    const uint4* hr4 = (const uint4*)(hbh2 + (size_t)n * 32);
#pragma unroll
    for (int q = 0; q < 8; ++q) {
        uint4 qq = hr4[q];
        uint uu[4] = {qq.x, qq.y, qq.z, qq.w};
#pragma unroll
        for (int j = 0; j < 4; ++j) {
            U2H hh; hh.u = uu[j];
            float f0 = (float)hh.h.x, f1 = (float)hh.h.y;
            int k = q * 8 + j * 2;
            const float* wl0 = W2l + k * NC;
            const float* wr0 = W2r + k * NC;
#pragma unroll
            for (int c = 0; c < NC; ++c) {
                al[c] = fmaf(f0, wl0[c], fmaf(f1, wl0[NC + c], al[c]));
                ar[c] = fmaf(f0, wr0[c], fmaf(f1, wr0[NC + c], ar[c]));
            }
        }
    }
    uint p0 = pkrtz_u(al[0], al[1]);
    uint p1 = pkrtz_u(al[2], al[3]);
    uint p2 = pkrtz_u(al[4], al[5]);
    uint p3 = pkrtz_u(al[6], al[7]);
    uint p4 = pkrtz_u(al[8], al[9]);
    *(uint4*)&xl2h[(size_t)n * 8]     = make_uint4(p0, p1, p2, p3);
    *(uint4*)&xl2h[(size_t)n * 8 + 4] = make_uint4(p4, 0u, 0u, 0u);
    p0 = pkrtz_u(ar[0], ar[1]);
    p1 = pkrtz_u(ar[2], ar[3]);
    p2 = pkrtz_u(ar[4], ar[5]);
    p3 = pkrtz_u(ar[6], ar[7]);
    p4 = pkrtz_u(ar[8], ar[9]);
    *(uint4*)&xr2h[(size_t)n * 8]     = make_uint4(p0, p1, p2, p3);
    *(uint4*)&xr2h[(size_t)n * 8 + 4] = make_uint4(p4, 0u, 0u, 0u);
}

// ---------------- layer 2 aggregate: masked batch-4, exp2 ----------------

__global__ __launch_bounds__(256) void k_agg2(const uint* __restrict__ xl2h,
                                              const uint* __restrict__ xr2h,
                                              const int* __restrict__ rowptr,
                                              const int* __restrict__ deg,
                                              const int* __restrict__ csr_src,
                                              const float* __restrict__ att2,
                                              const float* __restrict__ b2,
                                              float* __restrict__ out) {
    const int node = blockIdx.x * 4 + (threadIdx.x >> 6);
    if (node >= NN) return;
    const int lane = threadIdx.x & 63;
    const int fp = lane & 7;
    const int eg = lane >> 3;
    U2H att;
    if (fp < 5) {
        float2 av = *(const float2*)&att2[2 * fp];
        att.u = pkrtz_u(av.x * LOG2E, av.y * LOG2E);
    } else {
        att.u = 0;
    }
    U2H xrf; xrf.u = xr2h[(size_t)node * 8 + fp];
    const int start = rowptr[node];
    const int dg = deg[node];
    const int permbase = eg * 4;

    float denom = 0.f, acc0 = 0.f, acc1 = 0.f;
    for (int base = 0; base < dg; base += 64) {
        int idx = base + lane;
        int srcs = (idx < dg) ? csr_src[start + idx] : 0;
        int rem = dg - base; if (rem > 64) rem = 64;
        int iters = (rem + 7) >> 3;
        int thr = (rem - eg + 7) >> 3;
        for (int jj = 0; jj < iters; jj += 4) {
            int s[4]; U2H v[4];
#pragma unroll
            for (int k = 0; k < 4; ++k)
                s[k] = __builtin_amdgcn_ds_bpermute((jj + k) * 32 + permbase, srcs);
#pragma unroll
            for (int k = 0; k < 4; ++k)
                v[k].u = xl2h[(size_t)s[k] * 8 + fp];
#pragma unroll
            for (int k = 0; k < 4; ++k) {
                float tl = red8(dot2f(lrelu2(v[k].h + xrf.h), att.h, 0.f));
                float e = (jj + k < thr) ? exp2f(tl) : 0.f;
                denom += e;
                acc0 = fmaf(e, (float)v[k].h.x, acc0);
                acc1 = fmaf(e, (float)v[k].h.y, acc1);
            }
        }
    }
#pragma unroll
    for (int m = 8; m <= 32; m <<= 1) {
        denom += __shfl_xor(denom, m);
        acc0  += __shfl_xor(acc0, m);
        acc1  += __shfl_xor(acc1, m);
    }
    if (lane < 5) {
        float r = (dg > 0) ? (1.0f / denom) : 0.f;
        float2 o;
        o.x = fmaf(acc0, r, b2[2 * fp]);
        o.y = fmaf(acc1, r, b2[2 * fp + 1]);
        *(float2*)&out[(size_t)node * NC + 2 * fp] = o;
    }
}

// ---------------- launch ----------------

extern "C" void kernel_launch(void* const* d_in, const int* in_sizes, int n_in,
                              void* d_out, int out_size, void* d_ws, size_t ws_size,
                              hipStream_t stream) {
    const float* x    = (const float*)d_in[0];
    const int*   ei   = (const int*)d_in[1];
    const float* W1l  = (const float*)d_in[2];
    const float* W1r  = (const float*)d_in[3];
    const float* att1 = (const float*)d_in[4];
    const float* b1   = (const float*)d_in[5];
    const float* W2l  = (const float*)d_in[6];
    const float* W2r  = (const float*)d_in[7];
    const float* att2 = (const float*)d_in[8];
    const float* b2   = (const float*)d_in[9];
    float* out = (float*)d_out;

    char* w = (char*)d_ws;
    size_t off = 0;
    auto alloc = [&](size_t bytes) -> void* {
        void* p = w + off;
        off = (off + bytes + 255) & ~(size_t)255;
        return p;
    };
    uint* xlh2   = (uint*)alloc((size_t)NN * 32 * 4);
    uint* xrh2   = (uint*)alloc((size_t)NN * 32 * 4);
    uint* hbh2   = (uint*)alloc((size_t)NN * 32 * 4);
    uint* xl2h   = (uint*)alloc((size_t)NN * 8 * 4);
    uint* xr2h   = (uint*)alloc((size_t)NN * 8 * 4);
    uint* temp   = (uint*)alloc((size_t)P1B * CHUNK * 4);
    int*  lbmat  = (int*)alloc((size_t)P1B * LBW * 4);
    int*  rowptr = (int*)alloc((size_t)NN * 4);
    int*  deg    = (int*)alloc((size_t)NN * 4);
    int*  csr_src = (int*)alloc((size_t)(NE + 64) * 4);

    k_fusedA<<<P1B + GMT, 256, 0, stream>>>(x, ei, W1l, W1r,
                                            (_Float16*)xlh2, (_Float16*)xrh2,
                                            temp, lbmat);
    k_pass2<<<NB, 256, 0, stream>>>(temp, lbmat, rowptr, deg, csr_src);
    k_agg1<<<(NN + 3) / 4, 256, 0, stream>>>(xlh2, xrh2, rowptr, deg, csr_src, att1, b1, hbh2);
    k_gemm2<<<(NN + 255) / 256, 256, 0, stream>>>(hbh2, W2l, W2r, xl2h, xr2h);
    k_agg2<<<(NN + 3) / 4, 256, 0, stream>>>(xl2h, xr2h, rowptr, deg, csr_src, att2, b2, out);
}